// Round 2
// baseline (188.226 us; speedup 1.0000x reference)
//
#include <hip/hip_runtime.h>
#include <hip/hip_bf16.h>

#define D_MODEL 1024
#define NUM_HEADS 16
#define D_HEAD 64
#define BATCH 2
#define SEQ 2048
#define TOKENS (BATCH * SEQ) /* 4096 */

typedef __attribute__((ext_vector_type(8))) short bf16x8;
typedef __attribute__((ext_vector_type(4))) float f32x4;
typedef __attribute__((ext_vector_type(2))) unsigned int uint2v;

typedef __attribute__((address_space(1))) const unsigned int as1_uint;
typedef __attribute__((address_space(3))) unsigned int as3_uint;

#define LOG2E 1.44269504088896340736f

// round-to-nearest-even fp32 -> bf16 (bit pattern)
static __device__ __forceinline__ unsigned short f2bf(float f) {
    unsigned int u = __builtin_bit_cast(unsigned int, f);
    u += 0x7fffu + ((u >> 16) & 1u);
    return (unsigned short)(u >> 16);
}

// packed fp32x2 -> bf16x2 (lowers to v_cvt_pk_bf16_f32 on gfx950)
static __device__ __forceinline__ unsigned int pk2bf(float a, float b) {
    __hip_bfloat162 h = __float22bfloat162_rn(float2{a, b});
    unsigned int u;
    __builtin_memcpy(&u, &h, 4);
    return u;
}

// native v_exp_f32 (2^x)
static __device__ __forceinline__ float fast_exp2(float x) {
    return __builtin_amdgcn_exp2f(x);
}

// ---------------------------------------------------------------------------
// One-shot fp32 -> bf16 conversion of x and the 4 weight matrices.
// ---------------------------------------------------------------------------
__global__ __launch_bounds__(256) void convert_bf16(
    const float* __restrict__ x,  const float* __restrict__ Wq,
    const float* __restrict__ Wk, const float* __restrict__ Wv,
    const float* __restrict__ Wp,
    unsigned short* __restrict__ xb,  unsigned short* __restrict__ Wqb,
    unsigned short* __restrict__ Wkb, unsigned short* __restrict__ Wvb,
    unsigned short* __restrict__ Wpb)
{
    int v = blockIdx.x * 256 + threadIdx.x;
    const float* s;
    unsigned short* d;
    int off;
    if (v < (1 << 20)) { s = x; d = xb; off = v; }
    else {
        int u = v - (1 << 20);
        int w = u >> 18;
        off = u & ((1 << 18) - 1);
        s = (w == 0) ? Wq : (w == 1) ? Wk : (w == 2) ? Wv : Wp;
        d = (w == 0) ? Wqb : (w == 1) ? Wkb : (w == 2) ? Wvb : Wpb;
    }
    float4 f = ((const float4*)s)[off];
    ushort4 o = { f2bf(f.x), f2bf(f.y), f2bf(f.z), f2bf(f.w) };
    ((ushort4*)d)[off] = o;
}

// ---------------------------------------------------------------------------
// QKV projection: Y = Xb @ Wb^T, bf16 operands. BK=64, source-swizzled
// global_load_lds staging. 512 threads = 8 waves of 64x32.
// blockIdx.z: 0->Q (pre-scaled by log2e), 1->K, 2->Vt ([b][h][dh][s]).
// ---------------------------------------------------------------------------
__global__ __launch_bounds__(512) void qkv_gemm(
    const unsigned short* __restrict__ xb,
    const unsigned short* __restrict__ Wqb, const unsigned short* __restrict__ Wkb,
    const unsigned short* __restrict__ Wvb,
    unsigned short* __restrict__ Q, unsigned short* __restrict__ Kb,
    unsigned short* __restrict__ Vt)
{
    const int m0 = blockIdx.x * 128;
    const int n0 = blockIdx.y * 128;
    const unsigned short* W = (blockIdx.z == 0) ? Wqb : (blockIdx.z == 1) ? Wkb : Wvb;

    __shared__ __attribute__((aligned(16))) unsigned short lA[128 * 64];
    __shared__ __attribute__((aligned(16))) unsigned short lB[128 * 64];

    const int t = threadIdx.x;
    const int wave = t >> 6, lane = t & 63;
    const int wm = (wave & 1) * 64, wn = (wave >> 1) * 32;
    const int l15 = lane & 15, quad = lane >> 4;
    const int sw = l15 & 7;

    f32x4 acc[4][2];
#pragma unroll
    for (int i = 0; i < 4; i++)
#pragma unroll
        for (int j = 0; j < 2; j++) acc[i][j] = (f32x4)0.f;

    for (int k0 = 0; k0 < D_MODEL; k0 += 64) {
        __syncthreads();
        // 1024 16B chunks per tile, 2 per thread per tile
#pragma unroll
        for (int i = 0; i < 2; i++) {
            int fbase = wave * 64 + i * 512;
            int f = fbase + lane;
            int row = f >> 3, cp = f & 7;
            int c = cp ^ (row & 7);
            __builtin_amdgcn_global_load_lds(
                (as1_uint*)&xb[(size_t)(m0 + row) * D_MODEL + k0 + c * 8],
                (as3_uint*)&lA[fbase * 8], 16, 0, 0);
            __builtin_amdgcn_global_load_lds(
                (as1_uint*)&W[(size_t)(n0 + row) * D_MODEL + k0 + c * 8],
                (as3_uint*)&lB[fbase * 8], 16, 0, 0);
        }
        __syncthreads();

#pragma unroll
        for (int kk = 0; kk < 2; kk++) {
            const int cc = ((kk * 4 + quad) ^ sw) * 8;
            bf16x8 a[4], b[2];
#pragma unroll
            for (int mt = 0; mt < 4; mt++)
                a[mt] = *(const bf16x8*)&lA[(wm + mt * 16 + l15) * 64 + cc];
#pragma unroll
            for (int nt = 0; nt < 2; nt++)
                b[nt] = *(const bf16x8*)&lB[(wn + nt * 16 + l15) * 64 + cc];
#pragma unroll
            for (int mt = 0; mt < 4; mt++)
#pragma unroll
                for (int nt = 0; nt < 2; nt++)
                    acc[mt][nt] = __builtin_amdgcn_mfma_f32_16x16x32_bf16(
                        a[mt], b[nt], acc[mt][nt], 0, 0, 0);
        }
    }

    if (blockIdx.z == 2) {
        const int b = m0 >> 11;
        const int srow = (m0 & 2047) + wm + quad * 4;
#pragma unroll
        for (int mt = 0; mt < 4; mt++)
#pragma unroll
            for (int nt = 0; nt < 2; nt++) {
                int col = n0 + wn + nt * 16 + l15;
                int h = col >> 6, dh = col & 63;
                ushort4 pk = { f2bf(acc[mt][nt][0]), f2bf(acc[mt][nt][1]),
                               f2bf(acc[mt][nt][2]), f2bf(acc[mt][nt][3]) };
                *(ushort4*)&Vt[(size_t)((b * 16 + h) * 64 + dh) * SEQ + srow + mt * 16] = pk;
            }
    } else {
        unsigned short* Yo = (blockIdx.z == 0) ? Q : Kb;
        const float sc = (blockIdx.z == 0) ? LOG2E : 1.0f;
#pragma unroll
        for (int mt = 0; mt < 4; mt++)
#pragma unroll
            for (int nt = 0; nt < 2; nt++)
#pragma unroll
                for (int r = 0; r < 4; r++) {
                    int row = m0 + wm + mt * 16 + quad * 4 + r;
                    int col = n0 + wn + nt * 16 + l15;
                    Yo[(size_t)row * D_MODEL + col] = f2bf(acc[mt][nt][r] * sc);
                }
    }
}

// ---------------------------------------------------------------------------
// Flash attention. R18: P kept fully in-register -- the lP LDS round-trip
// (8x ds_write_b64 + 4x ds_read_b128 per wave/iter, ~29% of LDS traffic)
// is replaced by 16 cvt_pk + 16 permlane{32,16}_swap (VALU pipe, zero LDS).
// st layout: value(q=l15, s=16*mt+4*quad+r). PV A-frag needs (q=l15,
// k=quad*8+e). Per (kk,j): {U,V}=P32(W(2kk,j),W(2kk+1,j));
// {c=j, c=2+j}=P16(U,V). Verified elementwise (e.g. quad3/kk1/e7 -> s=63).
// s-split x2, XOR-swizzled K/V LDS, l via ones-MFMA, exp2 softmax.
// Block = (b,h, 128 q), 8 waves = 4 q-strips x 2 s-halves; 32 q/wave.
// 40 KB LDS (lP freed), grid-limited at 2 blocks/CU -> 16 waves/CU.
// ---------------------------------------------------------------------------
__global__ __launch_bounds__(512, 4) void attn(
    const unsigned short* __restrict__ Q, const unsigned short* __restrict__ K,
    const unsigned short* __restrict__ Vt, unsigned short* __restrict__ O)
{
    const int q0 = blockIdx.x * 128;
    const int bh = blockIdx.y;
    const int b = bh >> 4, h = bh & 15;
    const size_t base = (size_t)b * SEQ * D_MODEL + (size_t)h * D_HEAD;
    const size_t baseV = (size_t)bh * D_HEAD * SEQ;

    __shared__ __attribute__((aligned(16))) char smem[40960];
    unsigned short* lK0 = (unsigned short*)&smem[0];
    unsigned short* lV0 = (unsigned short*)&smem[16384];

    const int t = threadIdx.x;
    const int wave = t >> 6, lane = t & 63;
    const int l15 = lane & 15, quad = lane >> 4;
    const int wq = wave & 3;
    const int sh = wave >> 2;
    const int qw = q0 + wq * 32;
    const int sbase = sh * (SEQ / 2);

    unsigned short* lK  = lK0 + sh * 4096;
    unsigned short* lVt = lV0 + sh * 4096;

    bf16x8 ones;
#pragma unroll
    for (int i = 0; i < 8; i++) ones[i] = (short)0x3F80;

    bf16x8 bq[2][2];
#pragma unroll
    for (int mq = 0; mq < 2; mq++)
#pragma unroll
        for (int kk = 0; kk < 2; kk++)
            bq[mq][kk] = *(const bf16x8*)&Q[base +
                (size_t)(qw + mq * 16 + l15) * D_MODEL + kk * 32 + quad * 8];

    const int tl = t & 255;
    const int r0 = tl >> 3, c0 = tl & 7;
    const int cs = (c0 ^ (r0 & 7)) * 8;
    const unsigned short* gK0 = &K[base + (size_t)(sbase + r0) * D_MODEL + c0 * 8];
    const unsigned short* gK1 = &K[base + (size_t)(sbase + r0 + 32) * D_MODEL + c0 * 8];
    const unsigned short* gV0 = &Vt[baseV + (size_t)r0 * SEQ + sbase + c0 * 8];
    const unsigned short* gV1 = &Vt[baseV + (size_t)(r0 + 32) * SEQ + sbase + c0 * 8];

    const int sw = l15 & 7;

    f32x4 o_acc[2][4];
#pragma unroll
    for (int i = 0; i < 2; i++)
#pragma unroll
        for (int j = 0; j < 4; j++) o_acc[i][j] = (f32x4)0.f;
    f32x4 o_l[2];
#pragma unroll
    for (int i = 0; i < 2; i++) o_l[i] = (f32x4)0.f;

    uint4 rK0 = *(const uint4*)gK0;
    uint4 rK1 = *(const uint4*)gK1;
    uint4 rV0 = *(const uint4*)gV0;
    uint4 rV1 = *(const uint4*)gV1;

    for (int s0 = 0; s0 < SEQ / 2; s0 += 64) {
        __syncthreads();
        *(uint4*)&lK[r0 * 64 + cs]        = rK0;
        *(uint4*)&lK[(r0 + 32) * 64 + cs] = rK1;
        *(uint4*)&lVt[r0 * 64 + cs]        = rV0;
        *(uint4*)&lVt[(r0 + 32) * 64 + cs] = rV1;
        __syncthreads();

        int sn = (s0 + 64 < SEQ / 2) ? s0 + 64 : 0;
        rK0 = *(const uint4*)(gK0 + (size_t)sn * D_MODEL);
        rK1 = *(const uint4*)(gK1 + (size_t)sn * D_MODEL);
        rV0 = *(const uint4*)(gV0 + sn);
        rV1 = *(const uint4*)(gV1 + sn);

        f32x4 st[4][2];
#pragma unroll
        for (int mt = 0; mt < 4; mt++)
#pragma unroll
            for (int mq = 0; mq < 2; mq++) st[mt][mq] = (f32x4)0.f;
#pragma unroll
        for (int kk = 0; kk < 2; kk++) {
            const int cc = ((kk * 4 + quad) ^ sw) * 8;
#pragma unroll
            for (int mt = 0; mt < 4; mt++) {
                bf16x8 ak = *(const bf16x8*)&lK[(mt * 16 + l15) * 64 + cc];
#pragma unroll
                for (int mq = 0; mq < 2; mq++)
                    st[mt][mq] = __builtin_amdgcn_mfma_f32_16x16x32_bf16(
                        ak, bq[mq][kk], st[mt][mq], 0, 0, 0);
            }
        }

#pragma unroll
        for (int mq = 0; mq < 2; mq++)
#pragma unroll
            for (int mt = 0; mt < 4; mt++)
#pragma unroll
                for (int r = 0; r < 4; r++)
                    st[mt][mq][r] = fast_exp2(st[mt][mq][r]);

        // ---- P stays in registers: cvt_pk + permlane swaps build the PV
        // A-fragments directly (no LDS). Word W(mt,j)@quad holds
        // s2 = 8*mt + 2*quad + j; target word a[kk][c]@quad t needs
        // s2 = 16*kk + 4*t + c.  P32 then P16 realizes (reg<-b5, b5'<-b4).
        bf16x8 pa[2][2];
#pragma unroll
        for (int mq = 0; mq < 2; mq++)
#pragma unroll
            for (int kk = 0; kk < 2; kk++) {
                unsigned int cw[4];
#pragma unroll
                for (int j = 0; j < 2; j++) {
                    unsigned int w0 = pk2bf(st[2 * kk][mq][2 * j],
                                            st[2 * kk][mq][2 * j + 1]);
                    unsigned int w1 = pk2bf(st[2 * kk + 1][mq][2 * j],
                                            st[2 * kk + 1][mq][2 * j + 1]);
                    uint2v uv = __builtin_amdgcn_permlane32_swap(w0, w1, false, false);
                    uint2v f  = __builtin_amdgcn_permlane16_swap(uv[0], uv[1], false, false);
                    cw[j]     = f[0];
                    cw[2 + j] = f[1];
                }
                union { unsigned int w[4]; bf16x8 v; } u;
                u.w[0] = cw[0]; u.w[1] = cw[1]; u.w[2] = cw[2]; u.w[3] = cw[3];
                pa[mq][kk] = u.v;
            }

#pragma unroll
        for (int kk = 0; kk < 2; kk++) {
            const int cc = ((kk * 4 + quad) ^ sw) * 8;
            bf16x8 bv[4];
#pragma unroll
            for (int nt = 0; nt < 4; nt++)
                bv[nt] = *(const bf16x8*)&lVt[(nt * 16 + l15) * 64 + cc];
#pragma unroll
            for (int mq = 0; mq < 2; mq++) {
#pragma unroll
                for (int nt = 0; nt < 4; nt++)
                    o_acc[mq][nt] = __builtin_amdgcn_mfma_f32_16x16x32_bf16(
                        pa[mq][kk], bv[nt], o_acc[mq][nt], 0, 0, 0);
                o_l[mq] = __builtin_amdgcn_mfma_f32_16x16x32_bf16(
                    pa[mq][kk], ones, o_l[mq], 0, 0, 0);
            }
        }
    }

    float* sO = (float*)&smem[0];
    float* sL = (float*)&smem[36864];
    __syncthreads();
    if (sh == 1) {
#pragma unroll
        for (int mq = 0; mq < 2; mq++) {
#pragma unroll
            for (int r = 0; r < 4; r++)
                sL[wq * 32 + mq * 16 + quad * 4 + r] = o_l[mq][r];
#pragma unroll
            for (int nt = 0; nt < 4; nt++)
#pragma unroll
                for (int r = 0; r < 4; r++)
                    sO[(wq * 32 + mq * 16 + quad * 4 + r) * 68 + nt * 16 + l15] =
                        o_acc[mq][nt][r];
        }
    }
    __syncthreads();
    if (sh == 0) {
#pragma unroll
        for (int mq = 0; mq < 2; mq++) {
            float inv[4];
#pragma unroll
            for (int r = 0; r < 4; r++)
                inv[r] = 1.f / (o_l[mq][r] + sL[wq * 32 + mq * 16 + quad * 4 + r]);
#pragma unroll
            for (int nt = 0; nt < 4; nt++)
#pragma unroll
                for (int r = 0; r < 4; r++) {
                    int row = qw + mq * 16 + quad * 4 + r;
                    float v = o_acc[mq][nt][r] +
                              sO[(wq * 32 + mq * 16 + quad * 4 + r) * 68 + nt * 16 + l15];
                    O[base + (size_t)row * D_MODEL + nt * 16 + l15] = f2bf(v * inv[r]);
                }
        }
    }
}

// ---------------------------------------------------------------------------
// Output projection: out = O @ Wpb^T + bp. BK=64, source-swizzled staging,
// 512 threads = 8 waves of 64x32.
// ---------------------------------------------------------------------------
__global__ __launch_bounds__(512) void proj_gemm(
    const unsigned short* __restrict__ A, const unsigned short* __restrict__ W,
    const float* __restrict__ bias, float* __restrict__ out)
{
    const int m0 = blockIdx.x * 128;
    const int n0 = blockIdx.y * 128;

    __shared__ __attribute__((aligned(16))) unsigned short lA[128 * 64];
    __shared__ __attribute__((aligned(16))) unsigned short lB[128 * 64];

    const int t = threadIdx.x;
    const int wave = t >> 6, lane = t & 63;
    const int wm = (wave & 1) * 64, wn = (wave >> 1) * 32;
    const int l15 = lane & 15, quad = lane >> 4;
    const int sw = l15 & 7;

    f32x4 acc[4][2];
#pragma unroll
    for (int i = 0; i < 4; i++)
#pragma unroll
        for (int j = 0; j < 2; j++) acc[i][j] = (f32x4)0.f;

    for (int k0 = 0; k0 < D_MODEL; k0 += 64) {
        __syncthreads();
#pragma unroll
        for (int i = 0; i < 2; i++) {
            int fbase = wave * 64 + i * 512;
            int f = fbase + lane;
            int row = f >> 3, cp = f & 7;
            int c = cp ^ (row & 7);
            __builtin_amdgcn_global_load_lds(
                (as1_uint*)&A[(size_t)(m0 + row) * D_MODEL + k0 + c * 8],
                (as3_uint*)&lA[fbase * 8], 16, 0, 0);
            __builtin_amdgcn_global_load_lds(
                (as1_uint*)&W[(size_t)(n0 + row) * D_MODEL + k0 + c * 8],
                (as3_uint*)&lB[fbase * 8], 16, 0, 0);
        }
        __syncthreads();

#pragma unroll
        for (int kk = 0; kk < 2; kk++) {
            const int cc = ((kk * 4 + quad) ^ sw) * 8;
            bf16x8 a[4], b[2];
#pragma unroll
            for (int mt = 0; mt < 4; mt++)
                a[mt] = *(const bf16x8*)&lA[(wm + mt * 16 + l15) * 64 + cc];
#pragma unroll
            for (int nt = 0; nt < 2; nt++)
                b[nt] = *(const bf16x8*)&lB[(wn + nt * 16 + l15) * 64 + cc];
#pragma unroll
            for (int mt = 0; mt < 4; mt++)
#pragma unroll
                for (int nt = 0; nt < 2; nt++)
                    acc[mt][nt] = __builtin_amdgcn_mfma_f32_16x16x32_bf16(
                        a[mt], b[nt], acc[mt][nt], 0, 0, 0);
        }
    }

#pragma unroll
    for (int mt = 0; mt < 4; mt++)
#pragma unroll
        for (int nt = 0; nt < 2; nt++)
#pragma unroll
            for (int r = 0; r < 4; r++) {
                int row = m0 + wm + mt * 16 + quad * 4 + r;
                int col = n0 + wn + nt * 16 + l15;
                out[(size_t)row * D_MODEL + col] = acc[mt][nt][r] + bias[col];
            }
}

extern "C" void kernel_launch(void* const* d_in, const int* in_sizes, int n_in,
                              void* d_out, int out_size, void* d_ws, size_t ws_size,
                              hipStream_t stream)
{
    const float* x  = (const float*)d_in[0];
    const float* Wq = (const float*)d_in[2];
    const float* Wk = (const float*)d_in[3];
    const float* Wv = (const float*)d_in[4];
    const float* Wp = (const float*)d_in[5];
    const float* bp = (const float*)d_in[6];
    float* out = (float*)d_out;

    unsigned short* Q   = (unsigned short*)d_ws;
    unsigned short* K   = Q   + (size_t)TOKENS * D_MODEL;
    unsigned short* Vt  = K   + (size_t)TOKENS * D_MODEL;
    unsigned short* O   = Vt  + (size_t)TOKENS * D_MODEL;
    unsigned short* xb  = O   + (size_t)TOKENS * D_MODEL;
    unsigned short* Wqb = xb  + (size_t)TOKENS * D_MODEL;
    unsigned short* Wkb = Wqb + (size_t)D_MODEL * D_MODEL;
    unsigned short* Wvb = Wkb + (size_t)D_MODEL * D_MODEL;
    unsigned short* Wpb = Wvb + (size_t)D_MODEL * D_MODEL;

    convert_bf16<<<8192, 256, 0, stream>>>(x, Wq, Wk, Wv, Wp,
                                           xb, Wqb, Wkb, Wvb, Wpb);
    qkv_gemm<<<dim3(TOKENS / 128, D_MODEL / 128, 3), 512, 0, stream>>>(
        xb, Wqb, Wkb, Wvb, Q, K, Vt);
    attn<<<dim3(SEQ / 128, BATCH * NUM_HEADS), 512, 0, stream>>>(Q, K, Vt, O);
    proj_gemm<<<dim3(TOKENS / 128, D_MODEL / 128), 512, 0, stream>>>(O, Wpb, bp, out);
}

// Round 3
// 185.689 us; speedup vs baseline: 1.0137x; 1.0137x over previous
//
#include <hip/hip_runtime.h>
#include <hip/hip_bf16.h>

#define D_MODEL 1024
#define NUM_HEADS 16
#define D_HEAD 64
#define BATCH 2
#define SEQ 2048
#define TOKENS (BATCH * SEQ) /* 4096 */

typedef __attribute__((ext_vector_type(8))) short bf16x8;
typedef __attribute__((ext_vector_type(4))) float f32x4;
typedef __attribute__((ext_vector_type(2))) unsigned int uint2v;

typedef __attribute__((address_space(1))) const unsigned int as1_uint;
typedef __attribute__((address_space(3))) unsigned int as3_uint;

#define LOG2E 1.44269504088896340736f

// round-to-nearest-even fp32 -> bf16 (bit pattern)
static __device__ __forceinline__ unsigned short f2bf(float f) {
    unsigned int u = __builtin_bit_cast(unsigned int, f);
    u += 0x7fffu + ((u >> 16) & 1u);
    return (unsigned short)(u >> 16);
}

// packed fp32x2 -> bf16x2 (lowers to v_cvt_pk_bf16_f32 on gfx950)
static __device__ __forceinline__ unsigned int pk2bf(float a, float b) {
    __hip_bfloat162 h = __float22bfloat162_rn(float2{a, b});
    unsigned int u;
    __builtin_memcpy(&u, &h, 4);
    return u;
}

// native v_exp_f32 (2^x)
static __device__ __forceinline__ float fast_exp2(float x) {
    return __builtin_amdgcn_exp2f(x);
}

// ---------------------------------------------------------------------------
// One-shot fp32 -> bf16 conversion of x and the 4 weight matrices.
// ---------------------------------------------------------------------------
__global__ __launch_bounds__(256) void convert_bf16(
    const float* __restrict__ x,  const float* __restrict__ Wq,
    const float* __restrict__ Wk, const float* __restrict__ Wv,
    const float* __restrict__ Wp,
    unsigned short* __restrict__ xb,  unsigned short* __restrict__ Wqb,
    unsigned short* __restrict__ Wkb, unsigned short* __restrict__ Wvb,
    unsigned short* __restrict__ Wpb)
{
    int v = blockIdx.x * 256 + threadIdx.x;
    const float* s;
    unsigned short* d;
    int off;
    if (v < (1 << 20)) { s = x; d = xb; off = v; }
    else {
        int u = v - (1 << 20);
        int w = u >> 18;
        off = u & ((1 << 18) - 1);
        s = (w == 0) ? Wq : (w == 1) ? Wk : (w == 2) ? Wv : Wp;
        d = (w == 0) ? Wqb : (w == 1) ? Wkb : (w == 2) ? Wvb : Wpb;
    }
    float4 f = ((const float4*)s)[off];
    ushort4 o = { f2bf(f.x), f2bf(f.y), f2bf(f.z), f2bf(f.w) };
    ((ushort4*)d)[off] = o;
}

// ---------------------------------------------------------------------------
// QKV projection: Y = Xb @ Wb^T, bf16 operands. BK=64, source-swizzled
// global_load_lds staging. 512 threads = 8 waves of 64x32.
// blockIdx.z: 0->Q (pre-scaled by log2e), 1->K, 2->Vt ([b][h][dh][s]).
// ---------------------------------------------------------------------------
__global__ __launch_bounds__(512) void qkv_gemm(
    const unsigned short* __restrict__ xb,
    const unsigned short* __restrict__ Wqb, const unsigned short* __restrict__ Wkb,
    const unsigned short* __restrict__ Wvb,
    unsigned short* __restrict__ Q, unsigned short* __restrict__ Kb,
    unsigned short* __restrict__ Vt)
{
    const int m0 = blockIdx.x * 128;
    const int n0 = blockIdx.y * 128;
    const unsigned short* W = (blockIdx.z == 0) ? Wqb : (blockIdx.z == 1) ? Wkb : Wvb;

    __shared__ __attribute__((aligned(16))) unsigned short lA[128 * 64];
    __shared__ __attribute__((aligned(16))) unsigned short lB[128 * 64];

    const int t = threadIdx.x;
    const int wave = t >> 6, lane = t & 63;
    const int wm = (wave & 1) * 64, wn = (wave >> 1) * 32;
    const int l15 = lane & 15, quad = lane >> 4;
    const int sw = l15 & 7;

    f32x4 acc[4][2];
#pragma unroll
    for (int i = 0; i < 4; i++)
#pragma unroll
        for (int j = 0; j < 2; j++) acc[i][j] = (f32x4)0.f;

    for (int k0 = 0; k0 < D_MODEL; k0 += 64) {
        __syncthreads();
        // 1024 16B chunks per tile, 2 per thread per tile
#pragma unroll
        for (int i = 0; i < 2; i++) {
            int fbase = wave * 64 + i * 512;
            int f = fbase + lane;
            int row = f >> 3, cp = f & 7;
            int c = cp ^ (row & 7);
            __builtin_amdgcn_global_load_lds(
                (as1_uint*)&xb[(size_t)(m0 + row) * D_MODEL + k0 + c * 8],
                (as3_uint*)&lA[fbase * 8], 16, 0, 0);
            __builtin_amdgcn_global_load_lds(
                (as1_uint*)&W[(size_t)(n0 + row) * D_MODEL + k0 + c * 8],
                (as3_uint*)&lB[fbase * 8], 16, 0, 0);
        }
        __syncthreads();

#pragma unroll
        for (int kk = 0; kk < 2; kk++) {
            const int cc = ((kk * 4 + quad) ^ sw) * 8;
            bf16x8 a[4], b[2];
#pragma unroll
            for (int mt = 0; mt < 4; mt++)
                a[mt] = *(const bf16x8*)&lA[(wm + mt * 16 + l15) * 64 + cc];
#pragma unroll
            for (int nt = 0; nt < 2; nt++)
                b[nt] = *(const bf16x8*)&lB[(wn + nt * 16 + l15) * 64 + cc];
#pragma unroll
            for (int mt = 0; mt < 4; mt++)
#pragma unroll
                for (int nt = 0; nt < 2; nt++)
                    acc[mt][nt] = __builtin_amdgcn_mfma_f32_16x16x32_bf16(
                        a[mt], b[nt], acc[mt][nt], 0, 0, 0);
        }
    }

    if (blockIdx.z == 2) {
        const int b = m0 >> 11;
        const int srow = (m0 & 2047) + wm + quad * 4;
#pragma unroll
        for (int mt = 0; mt < 4; mt++)
#pragma unroll
            for (int nt = 0; nt < 2; nt++) {
                int col = n0 + wn + nt * 16 + l15;
                int h = col >> 6, dh = col & 63;
                ushort4 pk = { f2bf(acc[mt][nt][0]), f2bf(acc[mt][nt][1]),
                               f2bf(acc[mt][nt][2]), f2bf(acc[mt][nt][3]) };
                *(ushort4*)&Vt[(size_t)((b * 16 + h) * 64 + dh) * SEQ + srow + mt * 16] = pk;
            }
    } else {
        unsigned short* Yo = (blockIdx.z == 0) ? Q : Kb;
        const float sc = (blockIdx.z == 0) ? LOG2E : 1.0f;
#pragma unroll
        for (int mt = 0; mt < 4; mt++)
#pragma unroll
            for (int nt = 0; nt < 2; nt++)
#pragma unroll
                for (int r = 0; r < 4; r++) {
                    int row = m0 + wm + mt * 16 + quad * 4 + r;
                    int col = n0 + wn + nt * 16 + l15;
                    Yo[(size_t)row * D_MODEL + col] = f2bf(acc[mt][nt][r] * sc);
                }
    }
}

// ---------------------------------------------------------------------------
// Flash attention. R19: LDS-double-buffered K/V, ONE barrier per iter.
// After the barrier, tile t+1 is written to buf[cur^1] CONCURRENTLY with
// compute of tile t from buf[cur] (writes/reads alternate buffers, so one
// barrier orders both hazards). Global prefetch keeps full-iter latency
// cover. T5 setprio around MFMA clusters. P in-register via cvt_pk +
// permlane{32,16}_swap (R18, bank-conflict-free). 64 KB LDS -> 2 blocks/CU.
// Block = (b,h, 128 q), 8 waves = 4 q-strips x 2 s-halves; 32 q/wave.
// ---------------------------------------------------------------------------
__global__ __launch_bounds__(512, 4) void attn(
    const unsigned short* __restrict__ Q, const unsigned short* __restrict__ K,
    const unsigned short* __restrict__ Vt, unsigned short* __restrict__ O)
{
    const int q0 = blockIdx.x * 128;
    const int bh = blockIdx.y;
    const int b = bh >> 4, h = bh & 15;
    const size_t base = (size_t)b * SEQ * D_MODEL + (size_t)h * D_HEAD;
    const size_t baseV = (size_t)bh * D_HEAD * SEQ;

    __shared__ __attribute__((aligned(16))) char smem[65536];
    // K tiles: byte off = buf*16384 + sh*8192, [0,32768)
    // V tiles: byte off = 32768 + buf*16384 + sh*8192

    const int t = threadIdx.x;
    const int wave = t >> 6, lane = t & 63;
    const int l15 = lane & 15, quad = lane >> 4;
    const int wq = wave & 3;
    const int sh = wave >> 2;
    const int qw = q0 + wq * 32;
    const int sbase = sh * (SEQ / 2);

    unsigned short* lKb = (unsigned short*)&smem[sh * 8192];
    unsigned short* lVb = (unsigned short*)&smem[32768 + sh * 8192];

    bf16x8 ones;
#pragma unroll
    for (int i = 0; i < 8; i++) ones[i] = (short)0x3F80;

    bf16x8 bq[2][2];
#pragma unroll
    for (int mq = 0; mq < 2; mq++)
#pragma unroll
        for (int kk = 0; kk < 2; kk++)
            bq[mq][kk] = *(const bf16x8*)&Q[base +
                (size_t)(qw + mq * 16 + l15) * D_MODEL + kk * 32 + quad * 8];

    const int tl = t & 255;
    const int r0 = tl >> 3, c0 = tl & 7;
    const int cs = (c0 ^ (r0 & 7)) * 8;
    const unsigned short* gK0 = &K[base + (size_t)(sbase + r0) * D_MODEL + c0 * 8];
    const unsigned short* gK1 = &K[base + (size_t)(sbase + r0 + 32) * D_MODEL + c0 * 8];
    const unsigned short* gV0 = &Vt[baseV + (size_t)r0 * SEQ + sbase + c0 * 8];
    const unsigned short* gV1 = &Vt[baseV + (size_t)(r0 + 32) * SEQ + sbase + c0 * 8];

    const int sw = l15 & 7;

    f32x4 o_acc[2][4];
#pragma unroll
    for (int i = 0; i < 2; i++)
#pragma unroll
        for (int j = 0; j < 4; j++) o_acc[i][j] = (f32x4)0.f;
    f32x4 o_l[2];
#pragma unroll
    for (int i = 0; i < 2; i++) o_l[i] = (f32x4)0.f;

    // ---- prologue: tile 0 -> regs -> buf0; tile 1 -> regs
    uint4 rK0 = *(const uint4*)gK0;
    uint4 rK1 = *(const uint4*)gK1;
    uint4 rV0 = *(const uint4*)gV0;
    uint4 rV1 = *(const uint4*)gV1;
    *(uint4*)&lKb[r0 * 64 + cs]        = rK0;
    *(uint4*)&lKb[(r0 + 32) * 64 + cs] = rK1;
    *(uint4*)&lVb[r0 * 64 + cs]        = rV0;
    *(uint4*)&lVb[(r0 + 32) * 64 + cs] = rV1;
    rK0 = *(const uint4*)(gK0 + (size_t)64 * D_MODEL);
    rK1 = *(const uint4*)(gK1 + (size_t)64 * D_MODEL);
    rV0 = *(const uint4*)(gV0 + 64);
    rV1 = *(const uint4*)(gV1 + 64);

    int cur = 0;
    for (int s0 = 0; s0 < SEQ / 2; s0 += 64) {
        __syncthreads();
        // write tile t+1 into buf[cur^1], overlapped with compute below
        if (s0 + 64 < SEQ / 2) {
            unsigned short* lKw = lKb + (cur ^ 1) * 8192;
            unsigned short* lVw = lVb + (cur ^ 1) * 8192;
            *(uint4*)&lKw[r0 * 64 + cs]        = rK0;
            *(uint4*)&lKw[(r0 + 32) * 64 + cs] = rK1;
            *(uint4*)&lVw[r0 * 64 + cs]        = rV0;
            *(uint4*)&lVw[(r0 + 32) * 64 + cs] = rV1;
        }
        // issue global loads for tile t+2 (full-iter latency cover)
        if (s0 + 128 < SEQ / 2) {
            int sn = s0 + 128;
            rK0 = *(const uint4*)(gK0 + (size_t)sn * D_MODEL);
            rK1 = *(const uint4*)(gK1 + (size_t)sn * D_MODEL);
            rV0 = *(const uint4*)(gV0 + sn);
            rV1 = *(const uint4*)(gV1 + sn);
        }
        const unsigned short* lKc = lKb + cur * 8192;
        const unsigned short* lVc = lVb + cur * 8192;

        f32x4 st[4][2];
#pragma unroll
        for (int mt = 0; mt < 4; mt++)
#pragma unroll
            for (int mq = 0; mq < 2; mq++) st[mt][mq] = (f32x4)0.f;
        __builtin_amdgcn_s_setprio(1);
#pragma unroll
        for (int kk = 0; kk < 2; kk++) {
            const int cc = ((kk * 4 + quad) ^ sw) * 8;
#pragma unroll
            for (int mt = 0; mt < 4; mt++) {
                bf16x8 ak = *(const bf16x8*)&lKc[(mt * 16 + l15) * 64 + cc];
#pragma unroll
                for (int mq = 0; mq < 2; mq++)
                    st[mt][mq] = __builtin_amdgcn_mfma_f32_16x16x32_bf16(
                        ak, bq[mq][kk], st[mt][mq], 0, 0, 0);
            }
        }
        __builtin_amdgcn_s_setprio(0);

#pragma unroll
        for (int mq = 0; mq < 2; mq++)
#pragma unroll
            for (int mt = 0; mt < 4; mt++)
#pragma unroll
                for (int r = 0; r < 4; r++)
                    st[mt][mq][r] = fast_exp2(st[mt][mq][r]);

        // ---- P stays in registers: cvt_pk + permlane swaps build the PV
        // A-fragments directly (no LDS). Word W(mt,j)@quad holds
        // s2 = 8*mt + 2*quad + j; target word a[kk][c]@quad t needs
        // s2 = 16*kk + 4*t + c.  P32 then P16 realizes (reg<-b5, b5'<-b4).
        bf16x8 pa[2][2];
#pragma unroll
        for (int mq = 0; mq < 2; mq++)
#pragma unroll
            for (int kk = 0; kk < 2; kk++) {
                unsigned int cw[4];
#pragma unroll
                for (int j = 0; j < 2; j++) {
                    unsigned int w0 = pk2bf(st[2 * kk][mq][2 * j],
                                            st[2 * kk][mq][2 * j + 1]);
                    unsigned int w1 = pk2bf(st[2 * kk + 1][mq][2 * j],
                                            st[2 * kk + 1][mq][2 * j + 1]);
                    uint2v uv = __builtin_amdgcn_permlane32_swap(w0, w1, false, false);
                    uint2v f  = __builtin_amdgcn_permlane16_swap(uv[0], uv[1], false, false);
                    cw[j]     = f[0];
                    cw[2 + j] = f[1];
                }
                union { unsigned int w[4]; bf16x8 v; } u;
                u.w[0] = cw[0]; u.w[1] = cw[1]; u.w[2] = cw[2]; u.w[3] = cw[3];
                pa[mq][kk] = u.v;
            }

        __builtin_amdgcn_s_setprio(1);
#pragma unroll
        for (int kk = 0; kk < 2; kk++) {
            const int cc = ((kk * 4 + quad) ^ sw) * 8;
            bf16x8 bv[4];
#pragma unroll
            for (int nt = 0; nt < 4; nt++)
                bv[nt] = *(const bf16x8*)&lVc[(nt * 16 + l15) * 64 + cc];
#pragma unroll
            for (int mq = 0; mq < 2; mq++) {
#pragma unroll
                for (int nt = 0; nt < 4; nt++)
                    o_acc[mq][nt] = __builtin_amdgcn_mfma_f32_16x16x32_bf16(
                        pa[mq][kk], bv[nt], o_acc[mq][nt], 0, 0, 0);
                o_l[mq] = __builtin_amdgcn_mfma_f32_16x16x32_bf16(
                    pa[mq][kk], ones, o_l[mq], 0, 0, 0);
            }
        }
        __builtin_amdgcn_s_setprio(0);
        cur ^= 1;
    }

    float* sO = (float*)&smem[0];
    float* sL = (float*)&smem[36864];
    __syncthreads();
    if (sh == 1) {
#pragma unroll
        for (int mq = 0; mq < 2; mq++) {
#pragma unroll
            for (int r = 0; r < 4; r++)
                sL[wq * 32 + mq * 16 + quad * 4 + r] = o_l[mq][r];
#pragma unroll
            for (int nt = 0; nt < 4; nt++)
#pragma unroll
                for (int r = 0; r < 4; r++)
                    sO[(wq * 32 + mq * 16 + quad * 4 + r) * 68 + nt * 16 + l15] =
                        o_acc[mq][nt][r];
        }
    }
    __syncthreads();
    if (sh == 0) {
#pragma unroll
        for (int mq = 0; mq < 2; mq++) {
            float inv[4];
#pragma unroll
            for (int r = 0; r < 4; r++)
                inv[r] = 1.f / (o_l[mq][r] + sL[wq * 32 + mq * 16 + quad * 4 + r]);
#pragma unroll
            for (int nt = 0; nt < 4; nt++)
#pragma unroll
                for (int r = 0; r < 4; r++) {
                    int row = qw + mq * 16 + quad * 4 + r;
                    float v = o_acc[mq][nt][r] +
                              sO[(wq * 32 + mq * 16 + quad * 4 + r) * 68 + nt * 16 + l15];
                    O[base + (size_t)row * D_MODEL + nt * 16 + l15] = f2bf(v * inv[r]);
                }
        }
    }
}

// ---------------------------------------------------------------------------
// Output projection: out = O @ Wpb^T + bp. BK=64, source-swizzled staging,
// 512 threads = 8 waves of 64x32.
// ---------------------------------------------------------------------------
__global__ __launch_bounds__(512) void proj_gemm(
    const unsigned short* __restrict__ A, const unsigned short* __restrict__ W,
    const float* __restrict__ bias, float* __restrict__ out)
{
    const int m0 = blockIdx.x * 128;
    const int n0 = blockIdx.y * 128;

    __shared__ __attribute__((aligned(16))) unsigned short lA[128 * 64];
    __shared__ __attribute__((aligned(16))) unsigned short lB[128 * 64];

    const int t = threadIdx.x;
    const int wave = t >> 6, lane = t & 63;
    const int wm = (wave & 1) * 64, wn = (wave >> 1) * 32;
    const int l15 = lane & 15, quad = lane >> 4;
    const int sw = l15 & 7;

    f32x4 acc[4][2];
#pragma unroll
    for (int i = 0; i < 4; i++)
#pragma unroll
        for (int j = 0; j < 2; j++) acc[i][j] = (f32x4)0.f;

    for (int k0 = 0; k0 < D_MODEL; k0 += 64) {
        __syncthreads();
#pragma unroll
        for (int i = 0; i < 2; i++) {
            int fbase = wave * 64 + i * 512;
            int f = fbase + lane;
            int row = f >> 3, cp = f & 7;
            int c = cp ^ (row & 7);
            __builtin_amdgcn_global_load_lds(
                (as1_uint*)&A[(size_t)(m0 + row) * D_MODEL + k0 + c * 8],
                (as3_uint*)&lA[fbase * 8], 16, 0, 0);
            __builtin_amdgcn_global_load_lds(
                (as1_uint*)&W[(size_t)(n0 + row) * D_MODEL + k0 + c * 8],
                (as3_uint*)&lB[fbase * 8], 16, 0, 0);
        }
        __syncthreads();

#pragma unroll
        for (int kk = 0; kk < 2; kk++) {
            const int cc = ((kk * 4 + quad) ^ sw) * 8;
            bf16x8 a[4], b[2];
#pragma unroll
            for (int mt = 0; mt < 4; mt++)
                a[mt] = *(const bf16x8*)&lA[(wm + mt * 16 + l15) * 64 + cc];
#pragma unroll
            for (int nt = 0; nt < 2; nt++)
                b[nt] = *(const bf16x8*)&lB[(wn + nt * 16 + l15) * 64 + cc];
#pragma unroll
            for (int mt = 0; mt < 4; mt++)
#pragma unroll
                for (int nt = 0; nt < 2; nt++)
                    acc[mt][nt] = __builtin_amdgcn_mfma_f32_16x16x32_bf16(
                        a[mt], b[nt], acc[mt][nt], 0, 0, 0);
        }
    }

#pragma unroll
    for (int mt = 0; mt < 4; mt++)
#pragma unroll
        for (int nt = 0; nt < 2; nt++)
#pragma unroll
            for (int r = 0; r < 4; r++) {
                int row = m0 + wm + mt * 16 + quad * 4 + r;
                int col = n0 + wn + nt * 16 + l15;
                out[(size_t)row * D_MODEL + col] = acc[mt][nt][r] + bias[col];
            }
}

extern "C" void kernel_launch(void* const* d_in, const int* in_sizes, int n_in,
                              void* d_out, int out_size, void* d_ws, size_t ws_size,
                              hipStream_t stream)
{
    const float* x  = (const float*)d_in[0];
    const float* Wq = (const float*)d_in[2];
    const float* Wk = (const float*)d_in[3];
    const float* Wv = (const float*)d_in[4];
    const float* Wp = (const float*)d_in[5];
    const float* bp = (const float*)d_in[6];
    float* out = (float*)d_out;

    unsigned short* Q   = (unsigned short*)d_ws;
    unsigned short* K   = Q   + (size_t)TOKENS * D_MODEL;
    unsigned short* Vt  = K   + (size_t)TOKENS * D_MODEL;
    unsigned short* O   = Vt  + (size_t)TOKENS * D_MODEL;
    unsigned short* xb  = O   + (size_t)TOKENS * D_MODEL;
    unsigned short* Wqb = xb  + (size_t)TOKENS * D_MODEL;
    unsigned short* Wkb = Wqb + (size_t)D_MODEL * D_MODEL;
    unsigned short* Wvb = Wkb + (size_t)D_MODEL * D_MODEL;
    unsigned short* Wpb = Wvb + (size_t)D_MODEL * D_MODEL;

    convert_bf16<<<8192, 256, 0, stream>>>(x, Wq, Wk, Wv, Wp,
                                           xb, Wqb, Wkb, Wvb, Wpb);
    qkv_gemm<<<dim3(TOKENS / 128, D_MODEL / 128, 3), 512, 0, stream>>>(
        xb, Wqb, Wkb, Wvb, Q, K, Vt);
    attn<<<dim3(SEQ / 128, BATCH * NUM_HEADS), 512, 0, stream>>>(Q, K, Vt, O);
    proj_gemm<<<dim3(TOKENS / 128, D_MODEL / 128), 512, 0, stream>>>(O, Wpb, bp, out);
}

// Round 4
// 179.858 us; speedup vs baseline: 1.0465x; 1.0324x over previous
//
#include <hip/hip_runtime.h>
#include <hip/hip_bf16.h>

#define D_MODEL 1024
#define NUM_HEADS 16
#define D_HEAD 64
#define BATCH 2
#define SEQ 2048
#define TOKENS (BATCH * SEQ) /* 4096 */

typedef __attribute__((ext_vector_type(8))) short bf16x8;
typedef __attribute__((ext_vector_type(4))) float f32x4;
typedef __attribute__((ext_vector_type(2))) unsigned int uint2v;

typedef __attribute__((address_space(1))) const unsigned int as1_uint;
typedef __attribute__((address_space(3))) unsigned int as3_uint;

#define LOG2E 1.44269504088896340736f

// round-to-nearest-even fp32 -> bf16 (bit pattern)
static __device__ __forceinline__ unsigned short f2bf(float f) {
    unsigned int u = __builtin_bit_cast(unsigned int, f);
    u += 0x7fffu + ((u >> 16) & 1u);
    return (unsigned short)(u >> 16);
}

// packed fp32x2 -> bf16x2 (lowers to v_cvt_pk_bf16_f32 on gfx950)
static __device__ __forceinline__ unsigned int pk2bf(float a, float b) {
    __hip_bfloat162 h = __float22bfloat162_rn(float2{a, b});
    unsigned int u;
    __builtin_memcpy(&u, &h, 4);
    return u;
}

// native v_exp_f32 (2^x)
static __device__ __forceinline__ float fast_exp2(float x) {
    return __builtin_amdgcn_exp2f(x);
}

// ---------------------------------------------------------------------------
// One-shot fp32 -> bf16 conversion of x and the 4 weight matrices.
// ---------------------------------------------------------------------------
__global__ __launch_bounds__(256) void convert_bf16(
    const float* __restrict__ x,  const float* __restrict__ Wq,
    const float* __restrict__ Wk, const float* __restrict__ Wv,
    const float* __restrict__ Wp,
    unsigned short* __restrict__ xb,  unsigned short* __restrict__ Wqb,
    unsigned short* __restrict__ Wkb, unsigned short* __restrict__ Wvb,
    unsigned short* __restrict__ Wpb)
{
    int v = blockIdx.x * 256 + threadIdx.x;
    const float* s;
    unsigned short* d;
    int off;
    if (v < (1 << 20)) { s = x; d = xb; off = v; }
    else {
        int u = v - (1 << 20);
        int w = u >> 18;
        off = u & ((1 << 18) - 1);
        s = (w == 0) ? Wq : (w == 1) ? Wk : (w == 2) ? Wv : Wp;
        d = (w == 0) ? Wqb : (w == 1) ? Wkb : (w == 2) ? Wvb : Wpb;
    }
    float4 f = ((const float4*)s)[off];
    ushort4 o = { f2bf(f.x), f2bf(f.y), f2bf(f.z), f2bf(f.w) };
    ((ushort4*)d)[off] = o;
}

// ---------------------------------------------------------------------------
// R20: FUSED QKV projection. One block computes Q, K, AND V for its
// (m0,n0) tile: A (x) is staged ONCE per K-step and reused against the
// three weight tiles (A-HBM traffic /3, LDS reads per FLOP /1.8, barriers
// per FLOP /3). Double-buffered 64 KB tile-set (128 KB LDS total), ONE
// __syncthreads per K-step (its implicit vmcnt(0) drain completes the
// next tile's global_load_lds). Grid 32x8 = 256 blocks = 1/CU.
// Layout per buf: A @ buf*32768, B_z @ buf*32768 + (1+z)*8192 (shorts).
// ---------------------------------------------------------------------------
__global__ __launch_bounds__(512) void qkv_gemm(
    const unsigned short* __restrict__ xb,
    const unsigned short* __restrict__ Wqb, const unsigned short* __restrict__ Wkb,
    const unsigned short* __restrict__ Wvb,
    unsigned short* __restrict__ Q, unsigned short* __restrict__ Kb,
    unsigned short* __restrict__ Vt)
{
    const int m0 = blockIdx.x * 128;
    const int n0 = blockIdx.y * 128;

    __shared__ __attribute__((aligned(16))) unsigned short sm[65536]; // 128 KB

    const int t = threadIdx.x;
    const int wave = t >> 6, lane = t & 63;
    const int wm = (wave & 1) * 64, wn = (wave >> 1) * 32;
    const int l15 = lane & 15, quad = lane >> 4;
    const int sw = l15 & 7;

    const unsigned short* Wz[3] = { Wqb, Wkb, Wvb };

    f32x4 acc[3][4][2];
#pragma unroll
    for (int z = 0; z < 3; z++)
#pragma unroll
        for (int i = 0; i < 4; i++)
#pragma unroll
            for (int j = 0; j < 2; j++) acc[z][i][j] = (f32x4)0.f;

    // staging: 1024 16B chunks per matrix; thread covers 2 chunk-slots x 4 mats
    auto stage = [&](int k0, int buf) {
#pragma unroll
        for (int i = 0; i < 2; i++) {
            int fbase = wave * 64 + i * 512;
            int f = fbase + lane;
            int row = f >> 3, cp = f & 7;
            int c = cp ^ (row & 7);
            int srcc = k0 + c * 8;
            __builtin_amdgcn_global_load_lds(
                (as1_uint*)&xb[(size_t)(m0 + row) * D_MODEL + srcc],
                (as3_uint*)&sm[buf * 32768 + fbase * 8], 16, 0, 0);
#pragma unroll
            for (int z = 0; z < 3; z++)
                __builtin_amdgcn_global_load_lds(
                    (as1_uint*)&Wz[z][(size_t)(n0 + row) * D_MODEL + srcc],
                    (as3_uint*)&sm[buf * 32768 + (1 + z) * 8192 + fbase * 8],
                    16, 0, 0);
        }
    };

    stage(0, 0);
    __syncthreads();

    int cur = 0;
    for (int k0 = 0; k0 < D_MODEL; k0 += 64) {
        if (k0 + 64 < D_MODEL) stage(k0 + 64, cur ^ 1);

        const unsigned short* lA = &sm[cur * 32768];
#pragma unroll
        for (int kk = 0; kk < 2; kk++) {
            const int cc = ((kk * 4 + quad) ^ sw) * 8;
            bf16x8 a[4];
#pragma unroll
            for (int mt = 0; mt < 4; mt++)
                a[mt] = *(const bf16x8*)&lA[(wm + mt * 16 + l15) * 64 + cc];
#pragma unroll
            for (int z = 0; z < 3; z++) {
                const unsigned short* lB = &sm[cur * 32768 + (1 + z) * 8192];
                bf16x8 b[2];
#pragma unroll
                for (int nt = 0; nt < 2; nt++)
                    b[nt] = *(const bf16x8*)&lB[(wn + nt * 16 + l15) * 64 + cc];
#pragma unroll
                for (int mt = 0; mt < 4; mt++)
#pragma unroll
                    for (int nt = 0; nt < 2; nt++)
                        acc[z][mt][nt] = __builtin_amdgcn_mfma_f32_16x16x32_bf16(
                            a[mt], b[nt], acc[z][mt][nt], 0, 0, 0);
            }
        }
        __syncthreads();   // implicit vmcnt(0): next tile landed; cur free to refill
        cur ^= 1;
    }

    // ---- epilogue: Q (scaled by log2e), K, Vt ([b][h][dh][s])
#pragma unroll
    for (int mt = 0; mt < 4; mt++)
#pragma unroll
        for (int nt = 0; nt < 2; nt++)
#pragma unroll
            for (int r = 0; r < 4; r++) {
                int row = m0 + wm + mt * 16 + quad * 4 + r;
                int col = n0 + wn + nt * 16 + l15;
                Q[(size_t)row * D_MODEL + col]  = f2bf(acc[0][mt][nt][r] * LOG2E);
                Kb[(size_t)row * D_MODEL + col] = f2bf(acc[1][mt][nt][r]);
            }
    {
        const int b = m0 >> 11;
        const int srow = (m0 & 2047) + wm + quad * 4;
#pragma unroll
        for (int mt = 0; mt < 4; mt++)
#pragma unroll
            for (int nt = 0; nt < 2; nt++) {
                int col = n0 + wn + nt * 16 + l15;
                int h = col >> 6, dh = col & 63;
                ushort4 pk = { f2bf(acc[2][mt][nt][0]), f2bf(acc[2][mt][nt][1]),
                               f2bf(acc[2][mt][nt][2]), f2bf(acc[2][mt][nt][3]) };
                *(ushort4*)&Vt[(size_t)((b * 16 + h) * 64 + dh) * SEQ + srow + mt * 16] = pk;
            }
    }
}

// ---------------------------------------------------------------------------
// Flash attention (R18 proven: 50.4 us) -- reverted from R19's dbuf/setprio
// experiment (51.7, regression). s-split x2, XOR-swizzled K/V LDS, l via
// ones-MFMA, exp2 softmax (Q pre-scaled by log2e). P fully in-register via
// cvt_pk + permlane{32,16}_swap (0 bank conflicts). 40 KB LDS.
// Block = (b,h, 128 q), 8 waves = 4 q-strips x 2 s-halves; 32 q/wave.
// ---------------------------------------------------------------------------
__global__ __launch_bounds__(512, 4) void attn(
    const unsigned short* __restrict__ Q, const unsigned short* __restrict__ K,
    const unsigned short* __restrict__ Vt, unsigned short* __restrict__ O)
{
    const int q0 = blockIdx.x * 128;
    const int bh = blockIdx.y;
    const int b = bh >> 4, h = bh & 15;
    const size_t base = (size_t)b * SEQ * D_MODEL + (size_t)h * D_HEAD;
    const size_t baseV = (size_t)bh * D_HEAD * SEQ;

    __shared__ __attribute__((aligned(16))) char smem[40960];
    unsigned short* lK0 = (unsigned short*)&smem[0];
    unsigned short* lV0 = (unsigned short*)&smem[16384];

    const int t = threadIdx.x;
    const int wave = t >> 6, lane = t & 63;
    const int l15 = lane & 15, quad = lane >> 4;
    const int wq = wave & 3;
    const int sh = wave >> 2;
    const int qw = q0 + wq * 32;
    const int sbase = sh * (SEQ / 2);

    unsigned short* lK  = lK0 + sh * 4096;
    unsigned short* lVt = lV0 + sh * 4096;

    bf16x8 ones;
#pragma unroll
    for (int i = 0; i < 8; i++) ones[i] = (short)0x3F80;

    bf16x8 bq[2][2];
#pragma unroll
    for (int mq = 0; mq < 2; mq++)
#pragma unroll
        for (int kk = 0; kk < 2; kk++)
            bq[mq][kk] = *(const bf16x8*)&Q[base +
                (size_t)(qw + mq * 16 + l15) * D_MODEL + kk * 32 + quad * 8];

    const int tl = t & 255;
    const int r0 = tl >> 3, c0 = tl & 7;
    const int cs = (c0 ^ (r0 & 7)) * 8;
    const unsigned short* gK0 = &K[base + (size_t)(sbase + r0) * D_MODEL + c0 * 8];
    const unsigned short* gK1 = &K[base + (size_t)(sbase + r0 + 32) * D_MODEL + c0 * 8];
    const unsigned short* gV0 = &Vt[baseV + (size_t)r0 * SEQ + sbase + c0 * 8];
    const unsigned short* gV1 = &Vt[baseV + (size_t)(r0 + 32) * SEQ + sbase + c0 * 8];

    const int sw = l15 & 7;

    f32x4 o_acc[2][4];
#pragma unroll
    for (int i = 0; i < 2; i++)
#pragma unroll
        for (int j = 0; j < 4; j++) o_acc[i][j] = (f32x4)0.f;
    f32x4 o_l[2];
#pragma unroll
    for (int i = 0; i < 2; i++) o_l[i] = (f32x4)0.f;

    uint4 rK0 = *(const uint4*)gK0;
    uint4 rK1 = *(const uint4*)gK1;
    uint4 rV0 = *(const uint4*)gV0;
    uint4 rV1 = *(const uint4*)gV1;

    for (int s0 = 0; s0 < SEQ / 2; s0 += 64) {
        __syncthreads();
        *(uint4*)&lK[r0 * 64 + cs]        = rK0;
        *(uint4*)&lK[(r0 + 32) * 64 + cs] = rK1;
        *(uint4*)&lVt[r0 * 64 + cs]        = rV0;
        *(uint4*)&lVt[(r0 + 32) * 64 + cs] = rV1;
        __syncthreads();

        int sn = (s0 + 64 < SEQ / 2) ? s0 + 64 : 0;
        rK0 = *(const uint4*)(gK0 + (size_t)sn * D_MODEL);
        rK1 = *(const uint4*)(gK1 + (size_t)sn * D_MODEL);
        rV0 = *(const uint4*)(gV0 + sn);
        rV1 = *(const uint4*)(gV1 + sn);

        f32x4 st[4][2];
#pragma unroll
        for (int mt = 0; mt < 4; mt++)
#pragma unroll
            for (int mq = 0; mq < 2; mq++) st[mt][mq] = (f32x4)0.f;
#pragma unroll
        for (int kk = 0; kk < 2; kk++) {
            const int cc = ((kk * 4 + quad) ^ sw) * 8;
#pragma unroll
            for (int mt = 0; mt < 4; mt++) {
                bf16x8 ak = *(const bf16x8*)&lK[(mt * 16 + l15) * 64 + cc];
#pragma unroll
                for (int mq = 0; mq < 2; mq++)
                    st[mt][mq] = __builtin_amdgcn_mfma_f32_16x16x32_bf16(
                        ak, bq[mq][kk], st[mt][mq], 0, 0, 0);
            }
        }

#pragma unroll
        for (int mq = 0; mq < 2; mq++)
#pragma unroll
            for (int mt = 0; mt < 4; mt++)
#pragma unroll
                for (int r = 0; r < 4; r++)
                    st[mt][mq][r] = fast_exp2(st[mt][mq][r]);

        // ---- P stays in registers: cvt_pk + permlane swaps build the PV
        // A-fragments directly (no LDS). Word W(mt,j)@quad holds
        // s2 = 8*mt + 2*quad + j; target word a[kk][c]@quad t needs
        // s2 = 16*kk + 4*t + c.  P32 then P16 realizes (reg<-b5, b5'<-b4).
        bf16x8 pa[2][2];
#pragma unroll
        for (int mq = 0; mq < 2; mq++)
#pragma unroll
            for (int kk = 0; kk < 2; kk++) {
                unsigned int cw[4];
#pragma unroll
                for (int j = 0; j < 2; j++) {
                    unsigned int w0 = pk2bf(st[2 * kk][mq][2 * j],
                                            st[2 * kk][mq][2 * j + 1]);
                    unsigned int w1 = pk2bf(st[2 * kk + 1][mq][2 * j],
                                            st[2 * kk + 1][mq][2 * j + 1]);
                    uint2v uv = __builtin_amdgcn_permlane32_swap(w0, w1, false, false);
                    uint2v f  = __builtin_amdgcn_permlane16_swap(uv[0], uv[1], false, false);
                    cw[j]     = f[0];
                    cw[2 + j] = f[1];
                }
                union { unsigned int w[4]; bf16x8 v; } u;
                u.w[0] = cw[0]; u.w[1] = cw[1]; u.w[2] = cw[2]; u.w[3] = cw[3];
                pa[mq][kk] = u.v;
            }

#pragma unroll
        for (int kk = 0; kk < 2; kk++) {
            const int cc = ((kk * 4 + quad) ^ sw) * 8;
            bf16x8 bv[4];
#pragma unroll
            for (int nt = 0; nt < 4; nt++)
                bv[nt] = *(const bf16x8*)&lVt[(nt * 16 + l15) * 64 + cc];
#pragma unroll
            for (int mq = 0; mq < 2; mq++) {
#pragma unroll
                for (int nt = 0; nt < 4; nt++)
                    o_acc[mq][nt] = __builtin_amdgcn_mfma_f32_16x16x32_bf16(
                        pa[mq][kk], bv[nt], o_acc[mq][nt], 0, 0, 0);
                o_l[mq] = __builtin_amdgcn_mfma_f32_16x16x32_bf16(
                    pa[mq][kk], ones, o_l[mq], 0, 0, 0);
            }
        }
    }

    float* sO = (float*)&smem[0];
    float* sL = (float*)&smem[36864];
    __syncthreads();
    if (sh == 1) {
#pragma unroll
        for (int mq = 0; mq < 2; mq++) {
#pragma unroll
            for (int r = 0; r < 4; r++)
                sL[wq * 32 + mq * 16 + quad * 4 + r] = o_l[mq][r];
#pragma unroll
            for (int nt = 0; nt < 4; nt++)
#pragma unroll
                for (int r = 0; r < 4; r++)
                    sO[(wq * 32 + mq * 16 + quad * 4 + r) * 68 + nt * 16 + l15] =
                        o_acc[mq][nt][r];
        }
    }
    __syncthreads();
    if (sh == 0) {
#pragma unroll
        for (int mq = 0; mq < 2; mq++) {
            float inv[4];
#pragma unroll
            for (int r = 0; r < 4; r++)
                inv[r] = 1.f / (o_l[mq][r] + sL[wq * 32 + mq * 16 + quad * 4 + r]);
#pragma unroll
            for (int nt = 0; nt < 4; nt++)
#pragma unroll
                for (int r = 0; r < 4; r++) {
                    int row = qw + mq * 16 + quad * 4 + r;
                    float v = o_acc[mq][nt][r] +
                              sO[(wq * 32 + mq * 16 + quad * 4 + r) * 68 + nt * 16 + l15];
                    O[base + (size_t)row * D_MODEL + nt * 16 + l15] = f2bf(v * inv[r]);
                }
        }
    }
}

// ---------------------------------------------------------------------------
// Output projection: out = O @ Wpb^T + bp. BK=64, source-swizzled staging,
// 512 threads = 8 waves of 64x32.
// ---------------------------------------------------------------------------
__global__ __launch_bounds__(512) void proj_gemm(
    const unsigned short* __restrict__ A, const unsigned short* __restrict__ W,
    const float* __restrict__ bias, float* __restrict__ out)
{
    const int m0 = blockIdx.x * 128;
    const int n0 = blockIdx.y * 128;

    __shared__ __attribute__((aligned(16))) unsigned short lA[128 * 64];
    __shared__ __attribute__((aligned(16))) unsigned short lB[128 * 64];

    const int t = threadIdx.x;
    const int wave = t >> 6, lane = t & 63;
    const int wm = (wave & 1) * 64, wn = (wave >> 1) * 32;
    const int l15 = lane & 15, quad = lane >> 4;
    const int sw = l15 & 7;

    f32x4 acc[4][2];
#pragma unroll
    for (int i = 0; i < 4; i++)
#pragma unroll
        for (int j = 0; j < 2; j++) acc[i][j] = (f32x4)0.f;

    for (int k0 = 0; k0 < D_MODEL; k0 += 64) {
        __syncthreads();
#pragma unroll
        for (int i = 0; i < 2; i++) {
            int fbase = wave * 64 + i * 512;
            int f = fbase + lane;
            int row = f >> 3, cp = f & 7;
            int c = cp ^ (row & 7);
            __builtin_amdgcn_global_load_lds(
                (as1_uint*)&A[(size_t)(m0 + row) * D_MODEL + k0 + c * 8],
                (as3_uint*)&lA[fbase * 8], 16, 0, 0);
            __builtin_amdgcn_global_load_lds(
                (as1_uint*)&W[(size_t)(n0 + row) * D_MODEL + k0 + c * 8],
                (as3_uint*)&lB[fbase * 8], 16, 0, 0);
        }
        __syncthreads();

#pragma unroll
        for (int kk = 0; kk < 2; kk++) {
            const int cc = ((kk * 4 + quad) ^ sw) * 8;
            bf16x8 a[4], b[2];
#pragma unroll
            for (int mt = 0; mt < 4; mt++)
                a[mt] = *(const bf16x8*)&lA[(wm + mt * 16 + l15) * 64 + cc];
#pragma unroll
            for (int nt = 0; nt < 2; nt++)
                b[nt] = *(const bf16x8*)&lB[(wn + nt * 16 + l15) * 64 + cc];
#pragma unroll
            for (int mt = 0; mt < 4; mt++)
#pragma unroll
                for (int nt = 0; nt < 2; nt++)
                    acc[mt][nt] = __builtin_amdgcn_mfma_f32_16x16x32_bf16(
                        a[mt], b[nt], acc[mt][nt], 0, 0, 0);
        }
    }

#pragma unroll
    for (int mt = 0; mt < 4; mt++)
#pragma unroll
        for (int nt = 0; nt < 2; nt++)
#pragma unroll
            for (int r = 0; r < 4; r++) {
                int row = m0 + wm + mt * 16 + quad * 4 + r;
                int col = n0 + wn + nt * 16 + l15;
                out[(size_t)row * D_MODEL + col] = acc[mt][nt][r] + bias[col];
            }
}

extern "C" void kernel_launch(void* const* d_in, const int* in_sizes, int n_in,
                              void* d_out, int out_size, void* d_ws, size_t ws_size,
                              hipStream_t stream)
{
    const float* x  = (const float*)d_in[0];
    const float* Wq = (const float*)d_in[2];
    const float* Wk = (const float*)d_in[3];
    const float* Wv = (const float*)d_in[4];
    const float* Wp = (const float*)d_in[5];
    const float* bp = (const float*)d_in[6];
    float* out = (float*)d_out;

    unsigned short* Q   = (unsigned short*)d_ws;
    unsigned short* K   = Q   + (size_t)TOKENS * D_MODEL;
    unsigned short* Vt  = K   + (size_t)TOKENS * D_MODEL;
    unsigned short* O   = Vt  + (size_t)TOKENS * D_MODEL;
    unsigned short* xb  = O   + (size_t)TOKENS * D_MODEL;
    unsigned short* Wqb = xb  + (size_t)TOKENS * D_MODEL;
    unsigned short* Wkb = Wqb + (size_t)D_MODEL * D_MODEL;
    unsigned short* Wvb = Wkb + (size_t)D_MODEL * D_MODEL;
    unsigned short* Wpb = Wvb + (size_t)D_MODEL * D_MODEL;

    convert_bf16<<<8192, 256, 0, stream>>>(x, Wq, Wk, Wv, Wp,
                                           xb, Wqb, Wkb, Wvb, Wpb);
    qkv_gemm<<<dim3(TOKENS / 128, D_MODEL / 128), 512, 0, stream>>>(
        xb, Wqb, Wkb, Wvb, Q, K, Vt);
    attn<<<dim3(SEQ / 128, BATCH * NUM_HEADS), 512, 0, stream>>>(Q, K, Vt, O);
    proj_gemm<<<dim3(TOKENS / 128, D_MODEL / 128), 512, 0, stream>>>(O, Wpb, bp, out);
}

// Round 6
// 170.149 us; speedup vs baseline: 1.1062x; 1.0571x over previous
//
#include <hip/hip_runtime.h>
#include <hip/hip_bf16.h>

#define D_MODEL 1024
#define NUM_HEADS 16
#define D_HEAD 64
#define BATCH 2
#define SEQ 2048
#define TOKENS (BATCH * SEQ) /* 4096 */

typedef __attribute__((ext_vector_type(8))) short bf16x8;
typedef __attribute__((ext_vector_type(4))) float f32x4;
typedef __attribute__((ext_vector_type(2))) unsigned int uint2v;

typedef __attribute__((address_space(1))) const unsigned int as1_uint;
typedef __attribute__((address_space(3))) unsigned int as3_uint;

#define LOG2E 1.44269504088896340736f

// round-to-nearest-even fp32 -> bf16 (bit pattern)
static __device__ __forceinline__ unsigned short f2bf(float f) {
    unsigned int u = __builtin_bit_cast(unsigned int, f);
    u += 0x7fffu + ((u >> 16) & 1u);
    return (unsigned short)(u >> 16);
}

// packed fp32x2 -> bf16x2 (lowers to v_cvt_pk_bf16_f32 on gfx950)
static __device__ __forceinline__ unsigned int pk2bf(float a, float b) {
    __hip_bfloat162 h = __float22bfloat162_rn(float2{a, b});
    unsigned int u;
    __builtin_memcpy(&u, &h, 4);
    return u;
}

// native v_exp_f32 (2^x)
static __device__ __forceinline__ float fast_exp2(float x) {
    return __builtin_amdgcn_exp2f(x);
}

// ---------------------------------------------------------------------------
// One-shot fp32 -> bf16 conversion of x and the 4 weight matrices.
// ---------------------------------------------------------------------------
__global__ __launch_bounds__(256) void convert_bf16(
    const float* __restrict__ x,  const float* __restrict__ Wq,
    const float* __restrict__ Wk, const float* __restrict__ Wv,
    const float* __restrict__ Wp,
    unsigned short* __restrict__ xb,  unsigned short* __restrict__ Wqb,
    unsigned short* __restrict__ Wkb, unsigned short* __restrict__ Wvb,
    unsigned short* __restrict__ Wpb)
{
    int v = blockIdx.x * 256 + threadIdx.x;
    const float* s;
    unsigned short* d;
    int off;
    if (v < (1 << 20)) { s = x; d = xb; off = v; }
    else {
        int u = v - (1 << 20);
        int w = u >> 18;
        off = u & ((1 << 18) - 1);
        s = (w == 0) ? Wq : (w == 1) ? Wk : (w == 2) ? Wv : Wp;
        d = (w == 0) ? Wqb : (w == 1) ? Wkb : (w == 2) ? Wvb : Wpb;
    }
    float4 f = ((const float4*)s)[off];
    ushort4 o = { f2bf(f.x), f2bf(f.y), f2bf(f.z), f2bf(f.w) };
    ((ushort4*)d)[off] = o;
}

// ---------------------------------------------------------------------------
// R21: FUSED QKV projection, BN=64 for 2 blocks/CU. A (x) staged once per
// K-step, reused against 3 weight tiles. Per-buffer: A(128x64)=16KB +
// 3xB(64x64)=24KB -> 40KB; double-buffered = 80KB LDS -> 2 blocks/CU
// (R19 lesson: cross-block overlap hides barrier drains; 1 block/CU
// exposes the per-K-step vmcnt(0) drain). Grid 32x16 = 512 = 2/CU.
// ONE __syncthreads per K-step. acc = 3z x 4mt f32x4 = 48 VGPR.
// Layout per buf (shorts): A @ 0, B_z @ 8192 + z*4096. Buf stride 20480.
// ---------------------------------------------------------------------------
__global__ __launch_bounds__(512, 4) void qkv_gemm(
    const unsigned short* __restrict__ xb,
    const unsigned short* __restrict__ Wqb, const unsigned short* __restrict__ Wkb,
    const unsigned short* __restrict__ Wvb,
    unsigned short* __restrict__ Q, unsigned short* __restrict__ Kb,
    unsigned short* __restrict__ Vt)
{
    const int m0 = blockIdx.x * 128;
    const int n0 = blockIdx.y * 64;

    __shared__ __attribute__((aligned(16))) unsigned short sm[40960]; // 80 KB

    const int t = threadIdx.x;
    const int wave = t >> 6, lane = t & 63;
    const int wm = (wave & 1) * 64, wn = (wave >> 1) * 16;
    const int l15 = lane & 15, quad = lane >> 4;
    const int sw = l15 & 7;

    const unsigned short* Wz[3] = { Wqb, Wkb, Wvb };

    f32x4 acc[3][4];
#pragma unroll
    for (int z = 0; z < 3; z++)
#pragma unroll
        for (int i = 0; i < 4; i++) acc[z][i] = (f32x4)0.f;

    // A: 1024 16B chunks (2/thread); each B_z: 512 chunks (1/thread)
    auto stage = [&](int k0, int buf) {
#pragma unroll
        for (int i = 0; i < 2; i++) {
            int fbase = wave * 64 + i * 512;
            int f = fbase + lane;
            int row = f >> 3, cp = f & 7;
            int c = cp ^ (row & 7);
            __builtin_amdgcn_global_load_lds(
                (as1_uint*)&xb[(size_t)(m0 + row) * D_MODEL + k0 + c * 8],
                (as3_uint*)&sm[buf * 20480 + fbase * 8], 16, 0, 0);
        }
        {
            int row = t >> 3, cp = t & 7;
            int c = cp ^ (row & 7);
            int fbase = wave * 64;
#pragma unroll
            for (int z = 0; z < 3; z++)
                __builtin_amdgcn_global_load_lds(
                    (as1_uint*)&Wz[z][(size_t)(n0 + row) * D_MODEL + k0 + c * 8],
                    (as3_uint*)&sm[buf * 20480 + 8192 + z * 4096 + fbase * 8],
                    16, 0, 0);
        }
    };

    stage(0, 0);
    __syncthreads();

    int cur = 0;
    for (int k0 = 0; k0 < D_MODEL; k0 += 64) {
        if (k0 + 64 < D_MODEL) stage(k0 + 64, cur ^ 1);

        const unsigned short* lA = &sm[cur * 20480];
#pragma unroll
        for (int kk = 0; kk < 2; kk++) {
            const int cc = ((kk * 4 + quad) ^ sw) * 8;
            bf16x8 a[4];
#pragma unroll
            for (int mt = 0; mt < 4; mt++)
                a[mt] = *(const bf16x8*)&lA[(wm + mt * 16 + l15) * 64 + cc];
#pragma unroll
            for (int z = 0; z < 3; z++) {
                const unsigned short* lB = &sm[cur * 20480 + 8192 + z * 4096];
                bf16x8 b = *(const bf16x8*)&lB[(wn + l15) * 64 + cc];
#pragma unroll
                for (int mt = 0; mt < 4; mt++)
                    acc[z][mt] = __builtin_amdgcn_mfma_f32_16x16x32_bf16(
                        a[mt], b, acc[z][mt], 0, 0, 0);
            }
        }
        __syncthreads();   // implicit vmcnt(0): next tile landed; cur free
        cur ^= 1;
    }

    // ---- epilogue: Q (scaled by log2e), K, Vt ([b][h][dh][s])
#pragma unroll
    for (int mt = 0; mt < 4; mt++)
#pragma unroll
        for (int r = 0; r < 4; r++) {
            int row = m0 + wm + mt * 16 + quad * 4 + r;
            int col = n0 + wn + l15;
            Q[(size_t)row * D_MODEL + col]  = f2bf(acc[0][mt][r] * LOG2E);
            Kb[(size_t)row * D_MODEL + col] = f2bf(acc[1][mt][r]);
        }
    {
        const int b = m0 >> 11;
        const int srow = (m0 & 2047) + wm + quad * 4;
        const int h = n0 >> 6;
        const int dh = wn + l15;
#pragma unroll
        for (int mt = 0; mt < 4; mt++) {
            ushort4 pk = { f2bf(acc[2][mt][0]), f2bf(acc[2][mt][1]),
                           f2bf(acc[2][mt][2]), f2bf(acc[2][mt][3]) };
            *(ushort4*)&Vt[(size_t)((b * 16 + h) * 64 + dh) * SEQ + srow + mt * 16] = pk;
        }
    }
}

// ---------------------------------------------------------------------------
// Flash attention (R18 proven) -- s-split x2, XOR-swizzled K/V LDS, l via
// ones-MFMA, exp2 softmax (Q pre-scaled by log2e). P fully in-register via
// cvt_pk + permlane{32,16}_swap (0 bank conflicts). 40 KB LDS.
// Block = (b,h, 128 q), 8 waves = 4 q-strips x 2 s-halves; 32 q/wave.
// ---------------------------------------------------------------------------
__global__ __launch_bounds__(512, 4) void attn(
    const unsigned short* __restrict__ Q, const unsigned short* __restrict__ K,
    const unsigned short* __restrict__ Vt, unsigned short* __restrict__ O)
{
    const int q0 = blockIdx.x * 128;
    const int bh = blockIdx.y;
    const int b = bh >> 4, h = bh & 15;
    const size_t base = (size_t)b * SEQ * D_MODEL + (size_t)h * D_HEAD;
    const size_t baseV = (size_t)bh * D_HEAD * SEQ;

    __shared__ __attribute__((aligned(16))) char smem[40960];
    unsigned short* lK0 = (unsigned short*)&smem[0];
    unsigned short* lV0 = (unsigned short*)&smem[16384];

    const int t = threadIdx.x;
    const int wave = t >> 6, lane = t & 63;
    const int l15 = lane & 15, quad = lane >> 4;
    const int wq = wave & 3;
    const int sh = wave >> 2;
    const int qw = q0 + wq * 32;
    const int sbase = sh * (SEQ / 2);

    unsigned short* lK  = lK0 + sh * 4096;
    unsigned short* lVt = lV0 + sh * 4096;

    bf16x8 ones;
#pragma unroll
    for (int i = 0; i < 8; i++) ones[i] = (short)0x3F80;

    bf16x8 bq[2][2];
#pragma unroll
    for (int mq = 0; mq < 2; mq++)
#pragma unroll
        for (int kk = 0; kk < 2; kk++)
            bq[mq][kk] = *(const bf16x8*)&Q[base +
                (size_t)(qw + mq * 16 + l15) * D_MODEL + kk * 32 + quad * 8];

    const int tl = t & 255;
    const int r0 = tl >> 3, c0 = tl & 7;
    const int cs = (c0 ^ (r0 & 7)) * 8;
    const unsigned short* gK0 = &K[base + (size_t)(sbase + r0) * D_MODEL + c0 * 8];
    const unsigned short* gK1 = &K[base + (size_t)(sbase + r0 + 32) * D_MODEL + c0 * 8];
    const unsigned short* gV0 = &Vt[baseV + (size_t)r0 * SEQ + sbase + c0 * 8];
    const unsigned short* gV1 = &Vt[baseV + (size_t)(r0 + 32) * SEQ + sbase + c0 * 8];

    const int sw = l15 & 7;

    f32x4 o_acc[2][4];
#pragma unroll
    for (int i = 0; i < 2; i++)
#pragma unroll
        for (int j = 0; j < 4; j++) o_acc[i][j] = (f32x4)0.f;
    f32x4 o_l[2];
#pragma unroll
    for (int i = 0; i < 2; i++) o_l[i] = (f32x4)0.f;

    uint4 rK0 = *(const uint4*)gK0;
    uint4 rK1 = *(const uint4*)gK1;
    uint4 rV0 = *(const uint4*)gV0;
    uint4 rV1 = *(const uint4*)gV1;

    for (int s0 = 0; s0 < SEQ / 2; s0 += 64) {
        __syncthreads();
        *(uint4*)&lK[r0 * 64 + cs]        = rK0;
        *(uint4*)&lK[(r0 + 32) * 64 + cs] = rK1;
        *(uint4*)&lVt[r0 * 64 + cs]        = rV0;
        *(uint4*)&lVt[(r0 + 32) * 64 + cs] = rV1;
        __syncthreads();

        int sn = (s0 + 64 < SEQ / 2) ? s0 + 64 : 0;
        rK0 = *(const uint4*)(gK0 + (size_t)sn * D_MODEL);
        rK1 = *(const uint4*)(gK1 + (size_t)sn * D_MODEL);
        rV0 = *(const uint4*)(gV0 + sn);
        rV1 = *(const uint4*)(gV1 + sn);

        f32x4 st[4][2];
#pragma unroll
        for (int mt = 0; mt < 4; mt++)
#pragma unroll
            for (int mq = 0; mq < 2; mq++) st[mt][mq] = (f32x4)0.f;
#pragma unroll
        for (int kk = 0; kk < 2; kk++) {
            const int cc = ((kk * 4 + quad) ^ sw) * 8;
#pragma unroll
            for (int mt = 0; mt < 4; mt++) {
                bf16x8 ak = *(const bf16x8*)&lK[(mt * 16 + l15) * 64 + cc];
#pragma unroll
                for (int mq = 0; mq < 2; mq++)
                    st[mt][mq] = __builtin_amdgcn_mfma_f32_16x16x32_bf16(
                        ak, bq[mq][kk], st[mt][mq], 0, 0, 0);
            }
        }

#pragma unroll
        for (int mq = 0; mq < 2; mq++)
#pragma unroll
            for (int mt = 0; mt < 4; mt++)
#pragma unroll
                for (int r = 0; r < 4; r++)
                    st[mt][mq][r] = fast_exp2(st[mt][mq][r]);

        // ---- P stays in registers: cvt_pk + permlane swaps build the PV
        // A-fragments directly (no LDS). Word W(mt,j)@quad holds
        // s2 = 8*mt + 2*quad + j; target word a[kk][c]@quad t needs
        // s2 = 16*kk + 4*t + c.  P32 then P16 realizes (reg<-b5, b5'<-b4).
        bf16x8 pa[2][2];
#pragma unroll
        for (int mq = 0; mq < 2; mq++)
#pragma unroll
            for (int kk = 0; kk < 2; kk++) {
                unsigned int cw[4];
#pragma unroll
                for (int j = 0; j < 2; j++) {
                    unsigned int w0 = pk2bf(st[2 * kk][mq][2 * j],
                                            st[2 * kk][mq][2 * j + 1]);
                    unsigned int w1 = pk2bf(st[2 * kk + 1][mq][2 * j],
                                            st[2 * kk + 1][mq][2 * j + 1]);
                    uint2v uv = __builtin_amdgcn_permlane32_swap(w0, w1, false, false);
                    uint2v f  = __builtin_amdgcn_permlane16_swap(uv[0], uv[1], false, false);
                    cw[j]     = f[0];
                    cw[2 + j] = f[1];
                }
                union { unsigned int w[4]; bf16x8 v; } u;
                u.w[0] = cw[0]; u.w[1] = cw[1]; u.w[2] = cw[2]; u.w[3] = cw[3];
                pa[mq][kk] = u.v;
            }

#pragma unroll
        for (int kk = 0; kk < 2; kk++) {
            const int cc = ((kk * 4 + quad) ^ sw) * 8;
            bf16x8 bv[4];
#pragma unroll
            for (int nt = 0; nt < 4; nt++)
                bv[nt] = *(const bf16x8*)&lVt[(nt * 16 + l15) * 64 + cc];
#pragma unroll
            for (int mq = 0; mq < 2; mq++) {
#pragma unroll
                for (int nt = 0; nt < 4; nt++)
                    o_acc[mq][nt] = __builtin_amdgcn_mfma_f32_16x16x32_bf16(
                        pa[mq][kk], bv[nt], o_acc[mq][nt], 0, 0, 0);
                o_l[mq] = __builtin_amdgcn_mfma_f32_16x16x32_bf16(
                    pa[mq][kk], ones, o_l[mq], 0, 0, 0);
            }
        }
    }

    float* sO = (float*)&smem[0];
    float* sL = (float*)&smem[36864];
    __syncthreads();
    if (sh == 1) {
#pragma unroll
        for (int mq = 0; mq < 2; mq++) {
#pragma unroll
            for (int r = 0; r < 4; r++)
                sL[wq * 32 + mq * 16 + quad * 4 + r] = o_l[mq][r];
#pragma unroll
            for (int nt = 0; nt < 4; nt++)
#pragma unroll
                for (int r = 0; r < 4; r++)
                    sO[(wq * 32 + mq * 16 + quad * 4 + r) * 68 + nt * 16 + l15] =
                        o_acc[mq][nt][r];
        }
    }
    __syncthreads();
    if (sh == 0) {
#pragma unroll
        for (int mq = 0; mq < 2; mq++) {
            float inv[4];
#pragma unroll
            for (int r = 0; r < 4; r++)
                inv[r] = 1.f / (o_l[mq][r] + sL[wq * 32 + mq * 16 + quad * 4 + r]);
#pragma unroll
            for (int nt = 0; nt < 4; nt++)
#pragma unroll
                for (int r = 0; r < 4; r++) {
                    int row = qw + mq * 16 + quad * 4 + r;
                    float v = o_acc[mq][nt][r] +
                              sO[(wq * 32 + mq * 16 + quad * 4 + r) * 68 + nt * 16 + l15];
                    O[base + (size_t)row * D_MODEL + nt * 16 + l15] = f2bf(v * inv[r]);
                }
        }
    }
}

// ---------------------------------------------------------------------------
// R21: Output projection, BN=64 + dbuf one-sync (same template as qkv).
// Per buf: A(128x64)=16KB + B(64x64)=8KB = 24KB; dbuf 48KB LDS.
// Grid 32x16 = 512 = 2 blocks/CU (was 1 block/CU grid-limited).
// ---------------------------------------------------------------------------
__global__ __launch_bounds__(512, 4) void proj_gemm(
    const unsigned short* __restrict__ A, const unsigned short* __restrict__ W,
    const float* __restrict__ bias, float* __restrict__ out)
{
    const int m0 = blockIdx.x * 128;
    const int n0 = blockIdx.y * 64;

    __shared__ __attribute__((aligned(16))) unsigned short sm[24576]; // 48 KB

    const int t = threadIdx.x;
    const int wave = t >> 6, lane = t & 63;
    const int wm = (wave & 1) * 64, wn = (wave >> 1) * 16;
    const int l15 = lane & 15, quad = lane >> 4;
    const int sw = l15 & 7;

    f32x4 acc[4];
#pragma unroll
    for (int i = 0; i < 4; i++) acc[i] = (f32x4)0.f;

    auto stage = [&](int k0, int buf) {
#pragma unroll
        for (int i = 0; i < 2; i++) {
            int fbase = wave * 64 + i * 512;
            int f = fbase + lane;
            int row = f >> 3, cp = f & 7;
            int c = cp ^ (row & 7);
            __builtin_amdgcn_global_load_lds(
                (as1_uint*)&A[(size_t)(m0 + row) * D_MODEL + k0 + c * 8],
                (as3_uint*)&sm[buf * 12288 + fbase * 8], 16, 0, 0);
        }
        {
            int row = t >> 3, cp = t & 7;
            int c = cp ^ (row & 7);
            int fbase = wave * 64;
            __builtin_amdgcn_global_load_lds(
                (as1_uint*)&W[(size_t)(n0 + row) * D_MODEL + k0 + c * 8],
                (as3_uint*)&sm[buf * 12288 + 8192 + fbase * 8], 16, 0, 0);
        }
    };

    stage(0, 0);
    __syncthreads();

    int cur = 0;
    for (int k0 = 0; k0 < D_MODEL; k0 += 64) {
        if (k0 + 64 < D_MODEL) stage(k0 + 64, cur ^ 1);

        const unsigned short* lA = &sm[cur * 12288];
        const unsigned short* lB = &sm[cur * 12288 + 8192];
#pragma unroll
        for (int kk = 0; kk < 2; kk++) {
            const int cc = ((kk * 4 + quad) ^ sw) * 8;
            bf16x8 a[4];
#pragma unroll
            for (int mt = 0; mt < 4; mt++)
                a[mt] = *(const bf16x8*)&lA[(wm + mt * 16 + l15) * 64 + cc];
            bf16x8 b = *(const bf16x8*)&lB[(wn + l15) * 64 + cc];
#pragma unroll
            for (int mt = 0; mt < 4; mt++)
                acc[mt] = __builtin_amdgcn_mfma_f32_16x16x32_bf16(
                    a[mt], b, acc[mt], 0, 0, 0);
        }
        __syncthreads();
        cur ^= 1;
    }

    const int col = n0 + wn + l15;
    const float bc = bias[col];
#pragma unroll
    for (int mt = 0; mt < 4; mt++)
#pragma unroll
        for (int r = 0; r < 4; r++) {
            int row = m0 + wm + mt * 16 + quad * 4 + r;
            out[(size_t)row * D_MODEL + col] = acc[mt][r] + bc;
        }
}

extern "C" void kernel_launch(void* const* d_in, const int* in_sizes, int n_in,
                              void* d_out, int out_size, void* d_ws, size_t ws_size,
                              hipStream_t stream)
{
    const float* x  = (const float*)d_in[0];
    const float* Wq = (const float*)d_in[2];
    const float* Wk = (const float*)d_in[3];
    const float* Wv = (const float*)d_in[4];
    const float* Wp = (const float*)d_in[5];
    const float* bp = (const float*)d_in[6];
    float* out = (float*)d_out;

    unsigned short* Q   = (unsigned short*)d_ws;
    unsigned short* K   = Q   + (size_t)TOKENS * D_MODEL;
    unsigned short* Vt  = K   + (size_t)TOKENS * D_MODEL;
    unsigned short* O   = Vt  + (size_t)TOKENS * D_MODEL;
    unsigned short* xb  = O   + (size_t)TOKENS * D_MODEL;
    unsigned short* Wqb = xb  + (size_t)TOKENS * D_MODEL;
    unsigned short* Wkb = Wqb + (size_t)D_MODEL * D_MODEL;
    unsigned short* Wvb = Wkb + (size_t)D_MODEL * D_MODEL;
    unsigned short* Wpb = Wvb + (size_t)D_MODEL * D_MODEL;

    convert_bf16<<<8192, 256, 0, stream>>>(x, Wq, Wk, Wv, Wp,
                                           xb, Wqb, Wkb, Wvb, Wpb);
    qkv_gemm<<<dim3(TOKENS / 128, D_MODEL / 64), 512, 0, stream>>>(
        xb, Wqb, Wkb, Wvb, Q, K, Vt);
    attn<<<dim3(SEQ / 128, BATCH * NUM_HEADS), 512, 0, stream>>>(Q, K, Vt, O);
    proj_gemm<<<dim3(TOKENS / 128, D_MODEL / 64), 512, 0, stream>>>(O, Wpb, bp, out);
}